// Round 1
// baseline (128.025 us; speedup 1.0000x reference)
//
#include <hip/hip_runtime.h>
#include <math.h>

#define WL   140
#define OFC  118
#define TDN  21
#define DCM  16
#define NBR  4
#define COUT 10
#define KS   9

// ws layout (floats): [0..117] selected attA row, [128..245] selected attB row,
//                     [256..295] branch feats (4 x 10)
#define WS_ATT_A 0
#define WS_ATT_B 128
#define WS_FEATS 256

// ---------------------------------------------------------------------------
// Kernel 1: the two 118-dim MHAs (tdA, tdB) + row selection. One block each.
// ---------------------------------------------------------------------------
__global__ __launch_bounds__(256) void td_kernel(
    const float* __restrict__ x,
    const float* __restrict__ inA_w, const float* __restrict__ inA_b,
    const float* __restrict__ outA_w, const float* __restrict__ outA_b,
    const float* __restrict__ inB_w, const float* __restrict__ inB_b,
    const float* __restrict__ outB_w, const float* __restrict__ outB_b,
    float* __restrict__ ws)
{
    const int b = blockIdx.x;           // 0 = A, 1 = B
    const float* __restrict__ in_w  = b ? inB_w  : inA_w;
    const float* __restrict__ in_b  = b ? inB_b  : inA_b;
    const float* __restrict__ out_w = b ? outB_w : outA_w;
    const float* __restrict__ out_b = b ? outB_b : outA_b;
    const float* __restrict__ wav   = x + (b ? 17 * WL : 0);

    __shared__ float eeg[16][OFC];     // 16 x 118
    __shared__ float kA[TDN][120];     // sliding windows, padded rows (8B/16B aligned)
    __shared__ float qp[16][OFC];      // q-proj; later reused as av = attn@vp
    __shared__ float kp[TDN][OFC];
    __shared__ float vp[TDN][OFC];
    __shared__ float attn[16][TDN];
    __shared__ float att[16][OFC];
    __shared__ float colsum[OFC];
    __shared__ float Ssum[16];
    __shared__ int   sel;

    const int tid = threadIdx.x;

    // stage inputs
    for (int e = tid; e < TDN * 120; e += 256) {
        int t = e / 120, j = e % 120;       // t+j <= 20+119 = 139 < 140, always valid
        kA[t][j] = wav[t + j];
    }
    for (int e = tid; e < 16 * OFC; e += 256) {
        int r = e / OFC, c = e % OFC;
        eeg[r][c] = x[(1 + r) * WL + (WL - OFC) + c];
    }
    __syncthreads();

    const float scale = 1.0f / sqrtf((float)OFC);

    // q/k/v projections: 58 rows x 118 outputs, dot-118 each (float2 loads)
    for (int e = tid; e < 58 * OFC; e += 256) {
        int r = e / OFC, o = e % OFC;
        const float2* w2;
        const float2* i2;
        float bias;
        if (r < 16) {
            w2 = (const float2*)(in_w + o * OFC);
            i2 = (const float2*)(&eeg[r][0]);
            bias = in_b[o];
        } else if (r < 37) {
            int t = r - 16;
            w2 = (const float2*)(in_w + (OFC + o) * OFC);
            i2 = (const float2*)(&kA[t][0]);
            bias = in_b[OFC + o];
        } else {
            int t = r - 37;
            w2 = (const float2*)(in_w + (2 * OFC + o) * OFC);
            i2 = (const float2*)(&kA[t][0]);
            bias = in_b[2 * OFC + o];
        }
        float s = 0.f;
        for (int j = 0; j < 59; ++j) {
            float2 a = i2[j], w = w2[j];
            s += a.x * w.x + a.y * w.y;
        }
        s += bias;
        if (r < 16)      qp[r][o]      = s * scale;
        else if (r < 37) kp[r - 16][o] = s;
        else             vp[r - 37][o] = s;
    }
    __syncthreads();

    // scores (16 x 21), each dot-118
    for (int e = tid; e < 16 * TDN; e += 256) {
        int i = e / TDN, t = e % TDN;
        const float2* a  = (const float2*)(&qp[i][0]);
        const float2* k2 = (const float2*)(&kp[t][0]);
        float s = 0.f;
        for (int j = 0; j < 59; ++j) {
            float2 u = a[j], v = k2[j];
            s += u.x * v.x + u.y * v.y;
        }
        attn[i][t] = s;
    }
    __syncthreads();

    // softmax rows (16 rows of 21)
    if (tid < 16) {
        float m = attn[tid][0];
        for (int t = 1; t < TDN; ++t) m = fmaxf(m, attn[tid][t]);
        float l = 0.f;
        for (int t = 0; t < TDN; ++t) {
            float p = __expf(attn[tid][t] - m);
            attn[tid][t] = p;
            l += p;
        }
        float inv = 1.f / l;
        for (int t = 0; t < TDN; ++t) attn[tid][t] *= inv;
    }
    __syncthreads();

    // av = attn @ vp  (16 x 118, dot-21) -> reuse qp buffer
    for (int e = tid; e < 16 * OFC; e += 256) {
        int i = e / OFC, o = e % OFC;
        float s = 0.f;
        for (int t = 0; t < TDN; ++t) s += attn[i][t] * vp[t][o];
        qp[i][o] = s;
    }
    __syncthreads();

    // att = av @ out_w.T + out_b  (16 x 118, dot-118)
    for (int e = tid; e < 16 * OFC; e += 256) {
        int i = e / OFC, o = e % OFC;
        const float2* a  = (const float2*)(&qp[i][0]);
        const float2* w2 = (const float2*)(out_w + o * OFC);
        float s = out_b[o];
        for (int j = 0; j < 59; ++j) {
            float2 u = a[j], w = w2[j];
            s += u.x * w.x + u.y * w.y;
        }
        att[i][o] = s;
    }
    __syncthreads();

    // S[i] = sum_j eeg[i][j] * (sum_m att[m][j])
    for (int j = tid; j < OFC; j += 256) {
        float s = 0.f;
        for (int m = 0; m < 16; ++m) s += att[m][j];
        colsum[j] = s;
    }
    __syncthreads();
    if (tid < 16) {
        float s = 0.f;
        for (int j = 0; j < OFC; ++j) s += eeg[tid][j] * colsum[j];
        Ssum[tid] = s;
    }
    __syncthreads();
    if (tid == 0) {
        int best = 0; float bv = Ssum[0];
        for (int i = 1; i < 16; ++i)
            if (Ssum[i] > bv) { bv = Ssum[i]; best = i; }   // first-max (jnp.argmax)
        sel = best;
    }
    __syncthreads();

    float* dst = ws + (b ? WS_ATT_B : WS_ATT_A);
    for (int j = tid; j < OFC; j += 256) dst[j] = att[sel][j];
}

// ---------------------------------------------------------------------------
// Kernel 2: the four 16-dim cross MHAs + conv + relu + max. One block each.
// ---------------------------------------------------------------------------
__global__ __launch_bounds__(256) void branch_kernel(
    const float* __restrict__ x,
    const float* __restrict__ wsf,
    const float* __restrict__ cm_in_w, const float* __restrict__ cm_in_b,
    const float* __restrict__ cm_out_w, const float* __restrict__ cm_out_b,
    const float* __restrict__ projA_w, const float* __restrict__ projB_w,
    const float* __restrict__ conv_w, const float* __restrict__ conv_b,
    float* __restrict__ feats)
{
    const int br  = blockIdx.x;
    const int tid = threadIdx.x;

    __shared__ float arow[2][OFC];      // selected attA / attB rows
    __shared__ float pvec[2][16];       // projA_w, projB_w
    __shared__ float w_inT[16][48];     // transposed cm_in_w[br]: [r][q]
    __shared__ float b_in[48];
    __shared__ float w_out[16 * 16];
    __shared__ float b_out[16];
    __shared__ float qkv[3 * OFC * 16]; // qp|kp|vp; later aliased as softmax partials
    __shared__ float o2[OFC][17];       // attn output rows (padded 17 vs bank conflicts)
    __shared__ float cw[COUT * 16 * KS];
    __shared__ float cb[COUT];
    __shared__ float y[COUT][112];

    // ---- stage parameters ----
    for (int e = tid; e < 2 * OFC; e += 256) {
        int wch = e / OFC, j = e % OFC;
        arow[wch][j] = wsf[(wch ? WS_ATT_B : WS_ATT_A) + j];
    }
    if (tid < 16) { pvec[0][tid] = projA_w[tid]; pvec[1][tid] = projB_w[tid]; }
    for (int e = tid; e < 768; e += 256) {
        int q = e / 16, r = e % 16;
        w_inT[r][q] = cm_in_w[br * 768 + e];
    }
    if (tid < 48) b_in[tid] = cm_in_b[br * 48 + tid];
    w_out[tid & 255] = cm_out_w[br * 256 + (tid & 255)];
    if (tid < 16) b_out[tid] = cm_out_b[br * 16 + tid];
    for (int e = tid; e < COUT * 16 * KS; e += 256) cw[e] = conv_w[br * COUT * 16 * KS + e];
    if (tid < COUT) cb[tid] = conv_b[br * COUT + tid];
    __syncthreads();

    // data/kv codes: 0=eeg, 1=wA, 2=wB
    int dcode, kcode;
    switch (br) {
        case 0:  dcode = 1; kcode = 0; break;
        case 1:  dcode = 0; kcode = 1; break;
        case 2:  dcode = 0; kcode = 2; break;
        default: dcode = 2; kcode = 0; break;
    }

    float* qp = qkv;
    float* kp = qkv + OFC * 16;
    float* vp = qkv + 2 * OFC * 16;

    // ---- q/k/v projections: 3 x 118 x 16, dot-16 ----
    for (int e = tid; e < 3 * OFC * 16; e += 256) {
        int sec = e / (OFC * 16);
        int rem = e - sec * OFC * 16;
        int j = rem / 16, o = rem % 16;
        int code = (sec == 0) ? dcode : kcode;
        float s = 0.f;
        if (code == 0) {
            for (int r = 0; r < 16; ++r)
                s += x[(1 + r) * WL + (WL - OFC) + j] * w_inT[r][sec * 16 + o];
        } else {
            float aj = arow[code - 1][j];
            float t = 0.f;
            for (int r = 0; r < 16; ++r)
                t += pvec[code - 1][r] * w_inT[r][sec * 16 + o];
            s = t * aj;
        }
        s += b_in[sec * 16 + o];
        if (sec == 0) s *= 0.25f;       // 1/sqrt(16)
        qkv[e] = s;
    }
    __syncthreads();

    // ---- flash attention over 118 kv positions, split in 2 groups of 59 ----
    const int g = tid >> 7;             // 0 or 1
    const int j = tid & 127;            // row
    float q[16], acc[16];
    float m = -INFINITY, l = 0.f;
    #pragma unroll
    for (int r = 0; r < 16; ++r) acc[r] = 0.f;

    if (j < OFC) {
        #pragma unroll
        for (int r = 0; r < 16; ++r) q[r] = qp[j * 16 + r];
        const int t0 = g * 59, t1 = t0 + 59;
        for (int t = t0; t < t1; ++t) {
            const float* krow = kp + t * 16;
            float s = 0.f;
            #pragma unroll
            for (int r = 0; r < 16; ++r) s += q[r] * krow[r];
            float mn = fmaxf(m, s);
            float c  = __expf(m - mn);  // first iter: exp(-inf)=0
            float p  = __expf(s - mn);
            l = l * c + p;
            const float* vrow = vp + t * 16;
            #pragma unroll
            for (int r = 0; r < 16; ++r) acc[r] = acc[r] * c + p * vrow[r];
            m = mn;
        }
    }
    __syncthreads();                    // all reads of qp/kp/vp complete

    // partials aliased over the (now dead) qkv region
    float* part_m   = qkv;              // [2][128]
    float* part_l   = qkv + 256;        // [2][128]
    float* part_acc = qkv + 512;        // [2][118][16]
    if (j < OFC) {
        part_m[g * 128 + j] = m;
        part_l[g * 128 + j] = l;
        #pragma unroll
        for (int r = 0; r < 16; ++r) part_acc[(g * OFC + j) * 16 + r] = acc[r];
    }
    __syncthreads();

    // merge + out-projection -> o2[j][c]
    if (tid < OFC) {
        float m0 = part_m[tid], m1 = part_m[128 + tid];
        float mm = fmaxf(m0, m1);
        float c0 = __expf(m0 - mm), c1 = __expf(m1 - mm);
        float ll = part_l[tid] * c0 + part_l[128 + tid] * c1;
        float inv = 1.f / ll;
        float orow[16];
        #pragma unroll
        for (int r = 0; r < 16; ++r)
            orow[r] = (part_acc[tid * 16 + r] * c0 + part_acc[(OFC + tid) * 16 + r] * c1) * inv;
        for (int c = 0; c < 16; ++c) {
            float s = b_out[c];
            #pragma unroll
            for (int mI = 0; mI < 16; ++mI) s += orow[mI] * w_out[c * 16 + mI];
            o2[tid][c] = s;
        }
    }
    __syncthreads();

    // ---- conv (VALID, width 110) + relu ----
    for (int e = tid; e < COUT * 110; e += 256) {
        int c = e / 110, p = e % 110;
        float s = cb[c];
        for (int mI = 0; mI < 16; ++mI) {
            #pragma unroll
            for (int k = 0; k < KS; ++k)
                s += o2[p + k][mI] * cw[(c * 16 + mI) * KS + k];
        }
        y[c][p] = fmaxf(s, 0.f);
    }
    __syncthreads();

    // ---- max over positions ----
    if (tid < COUT) {
        float mx = y[tid][0];
        for (int p = 1; p < 110; ++p) mx = fmaxf(mx, y[tid][p]);
        feats[br * COUT + tid] = mx;
    }
}

// ---------------------------------------------------------------------------
// Kernel 3: 40 -> 40 -> 2 sigmoid head
// ---------------------------------------------------------------------------
__global__ __launch_bounds__(64) void head_kernel(
    const float* __restrict__ feats,
    const float* __restrict__ fc1_w, const float* __restrict__ fc1_b,
    const float* __restrict__ fc2_w, const float* __restrict__ fc2_b,
    float* __restrict__ out)
{
    __shared__ float flat[40];
    __shared__ float h[40];
    const int tid = threadIdx.x;
    if (tid < 40) flat[tid] = feats[tid];
    __syncthreads();
    if (tid < 40) {
        float s = fc1_b[tid];
        for (int k = 0; k < 40; ++k) s += flat[k] * fc1_w[tid * 40 + k];
        h[tid] = 1.f / (1.f + __expf(-s));
    }
    __syncthreads();
    if (tid < 2) {
        float s = fc2_b[tid];
        for (int k = 0; k < 40; ++k) s += h[k] * fc2_w[tid * 40 + k];
        out[tid] = 1.f / (1.f + __expf(-s));
    }
}

// ---------------------------------------------------------------------------
extern "C" void kernel_launch(void* const* d_in, const int* in_sizes, int n_in,
                              void* d_out, int out_size, void* d_ws, size_t ws_size,
                              hipStream_t stream) {
    const float* x        = (const float*)d_in[0];
    const float* tdA_in_w = (const float*)d_in[1];
    const float* tdA_in_b = (const float*)d_in[2];
    const float* tdA_out_w= (const float*)d_in[3];
    const float* tdA_out_b= (const float*)d_in[4];
    const float* tdB_in_w = (const float*)d_in[5];
    const float* tdB_in_b = (const float*)d_in[6];
    const float* tdB_out_w= (const float*)d_in[7];
    const float* tdB_out_b= (const float*)d_in[8];
    const float* cm_in_w  = (const float*)d_in[9];
    const float* cm_in_b  = (const float*)d_in[10];
    const float* cm_out_w = (const float*)d_in[11];
    const float* cm_out_b = (const float*)d_in[12];
    const float* projA_w  = (const float*)d_in[13];
    const float* projB_w  = (const float*)d_in[14];
    const float* conv_w   = (const float*)d_in[15];
    const float* conv_b   = (const float*)d_in[16];
    const float* fc1_w    = (const float*)d_in[17];
    const float* fc1_b    = (const float*)d_in[18];
    const float* fc2_w    = (const float*)d_in[19];
    const float* fc2_b    = (const float*)d_in[20];

    float* ws  = (float*)d_ws;
    float* out = (float*)d_out;

    td_kernel<<<2, 256, 0, stream>>>(x,
        tdA_in_w, tdA_in_b, tdA_out_w, tdA_out_b,
        tdB_in_w, tdB_in_b, tdB_out_w, tdB_out_b, ws);

    branch_kernel<<<4, 256, 0, stream>>>(x, ws,
        cm_in_w, cm_in_b, cm_out_w, cm_out_b,
        projA_w, projB_w, conv_w, conv_b, ws + WS_FEATS);

    head_kernel<<<1, 64, 0, stream>>>(ws + WS_FEATS,
        fc1_w, fc1_b, fc2_w, fc2_b, out);
}

// Round 2
// 61.915 us; speedup vs baseline: 2.0677x; 2.0677x over previous
//
#include <hip/hip_runtime.h>
#include <math.h>

#define WL   140
#define OFC  118
#define TDN  21
#define DCM  16
#define NBR  4
#define COUT 10
#define KS   9

#define IW_SZ (OFC * OFC)          // 13924 floats per weight section

// ws layout (floats):
//   per b in {0,1}, base = b*6848:  qp[16][118] @ +0, kp[21][118] @ +1888, vp[21][118] @ +4368
//   selected rows:  attA @ 13696, attB @ 13824
//   branch feats:   @ 13952 (4 x 10)
#define PROJ_STRIDE 6848
#define KP_OFF      1888
#define VP_OFF      4368
#define WS_ATT_A    13696
#define WS_ATT_B    13824
#define WS_FEATS    13952

// ---------------------------------------------------------------------------
// Kernel 1: q/k/v projections for both td-MHAs. 6 blocks = {A,B} x {q,k,v}.
// Weight section staged in LDS (coalesced), dots read from LDS.
// ---------------------------------------------------------------------------
__global__ __launch_bounds__(512) void td_proj_kernel(
    const float* __restrict__ x,
    const float* __restrict__ inA_w, const float* __restrict__ inA_b,
    const float* __restrict__ inB_w, const float* __restrict__ inB_b,
    float* __restrict__ ws)
{
    const int blk = blockIdx.x;        // 0..5
    const int b   = blk / 3;
    const int sec = blk % 3;           // 0=q (eeg), 1=k, 2=v (wav windows)
    const float* __restrict__ in_w = (b ? inB_w : inA_w) + sec * IW_SZ;
    const float* __restrict__ in_b = (b ? inB_b : inA_b) + sec * OFC;
    const float* __restrict__ wav  = x + (b ? 17 * WL : 0);

    __shared__ float w[IW_SZ];         // 55.7 KB
    __shared__ float inp[21][120];     // eeg rows (16x118) or windows (21x120)

    const int tid = threadIdx.x;

    for (int e = tid; e < IW_SZ; e += 512) w[e] = in_w[e];   // coalesced
    if (sec == 0) {
        for (int e = tid; e < 16 * OFC; e += 512) {
            int r = e / OFC, c = e % OFC;
            inp[r][c] = x[(1 + r) * WL + (WL - OFC) + c];
        }
    } else {
        for (int e = tid; e < TDN * 120; e += 512) {
            int t = e / 120, j = e % 120;       // t+j <= 139, always valid
            inp[t][j] = wav[t + j];
        }
    }
    __syncthreads();

    const int   R     = (sec == 0) ? 16 : TDN;
    const float scale = (sec == 0) ? (1.0f / sqrtf((float)OFC)) : 1.0f;
    float* __restrict__ dst = ws + b * PROJ_STRIDE
                            + (sec == 0 ? 0 : (sec == 1 ? KP_OFF : VP_OFF));

    // 2 outputs per thread-iteration share the input row (118 = 59*2)
    for (int e = tid; e < R * 59; e += 512) {
        int r  = e / 59;
        int og = (e % 59) * 2;
        const float2* a  = (const float2*)&inp[r][0];
        const float2* w0 = (const float2*)&w[og * OFC];        // 118 even -> aligned
        const float2* w1 = (const float2*)&w[(og + 1) * OFC];
        float s0 = 0.f, s1 = 0.f;
        #pragma unroll 4
        for (int j = 0; j < 59; ++j) {
            float2 av = a[j], u = w0[j], v = w1[j];
            s0 += av.x * u.x + av.y * u.y;
            s1 += av.x * v.x + av.y * v.y;
        }
        dst[r * OFC + og]     = (s0 + in_b[og])     * scale;
        dst[r * OFC + og + 1] = (s1 + in_b[og + 1]) * scale;
    }
}

// ---------------------------------------------------------------------------
// Kernel 2: scores + softmax + row-selection, using the colsum trick:
//   S[i] = eeg[i] . colsum,  colsum[j] = (sum_m av[m]) . w_out[j] + 16*b[j],
//   sum_m av[m][k] = (sum_m attn[m]) . vp[:,k].
// Only the selected row's out-projection is materialized. 2 blocks (A, B).
// ---------------------------------------------------------------------------
__global__ __launch_bounds__(512) void td_attn_kernel(
    const float* __restrict__ x,
    const float* __restrict__ outA_w, const float* __restrict__ outA_b,
    const float* __restrict__ outB_w, const float* __restrict__ outB_b,
    float* __restrict__ ws)
{
    const int b = blockIdx.x;
    const float* __restrict__ out_w = b ? outB_w : outA_w;
    const float* __restrict__ out_b = b ? outB_b : outA_b;
    const float* __restrict__ base  = ws + b * PROJ_STRIDE;

    __shared__ float w[IW_SZ];          // 55.7 KB
    __shared__ float eeg[16][OFC];
    __shared__ float qp[16][OFC];
    __shared__ float kp[TDN][OFC];
    __shared__ float vp[TDN][OFC];
    __shared__ float attn[16][TDN];
    __shared__ float acs[TDN];          // column-sum of attn over the 16 rows
    __shared__ float avcs[OFC];         // sum_m av[m][k]
    __shared__ float colsum[OFC];
    __shared__ float Ssum[16];
    __shared__ float avsel[OFC];
    __shared__ int   sel;

    const int tid = threadIdx.x;
    float* qpf = &qp[0][0];
    float* kpf = &kp[0][0];
    float* vpf = &vp[0][0];

    for (int e = tid; e < IW_SZ; e += 512) w[e] = out_w[e];     // coalesced
    for (int e = tid; e < 16 * OFC; e += 512) {
        qpf[e] = base[e];
        int r = e / OFC, c = e % OFC;
        eeg[r][c] = x[(1 + r) * WL + (WL - OFC) + c];
    }
    for (int e = tid; e < TDN * OFC; e += 512) {
        kpf[e] = base[KP_OFF + e];
        vpf[e] = base[VP_OFF + e];
    }
    __syncthreads();

    // scores 16x21, dot-118 from LDS
    for (int e = tid; e < 16 * TDN; e += 512) {
        int i = e / TDN, t = e % TDN;
        const float2* a  = (const float2*)&qp[i][0];
        const float2* k2 = (const float2*)&kp[t][0];
        float s = 0.f;
        #pragma unroll 4
        for (int j = 0; j < 59; ++j) {
            float2 u = a[j], v = k2[j];
            s += u.x * v.x + u.y * v.y;
        }
        attn[i][t] = s;
    }
    __syncthreads();

    // softmax rows
    if (tid < 16) {
        float m = attn[tid][0];
        for (int t = 1; t < TDN; ++t) m = fmaxf(m, attn[tid][t]);
        float l = 0.f;
        for (int t = 0; t < TDN; ++t) {
            float p = __expf(attn[tid][t] - m);
            attn[tid][t] = p;
            l += p;
        }
        float inv = 1.f / l;
        for (int t = 0; t < TDN; ++t) attn[tid][t] *= inv;
    }
    __syncthreads();

    if (tid < TDN) {
        float s = 0.f;
        for (int i = 0; i < 16; ++i) s += attn[i][tid];
        acs[tid] = s;
    }
    __syncthreads();

    if (tid < OFC) {
        float s = 0.f;
        for (int t = 0; t < TDN; ++t) s += acs[t] * vp[t][tid];
        avcs[tid] = s;
    }
    __syncthreads();

    // colsum[j] = avcs . w[j] + 16*b[j]
    if (tid < OFC) {
        const float2* a  = (const float2*)&avcs[0];
        const float2* w2 = (const float2*)&w[tid * OFC];
        float s = 0.f;
        #pragma unroll 4
        for (int j = 0; j < 59; ++j) {
            float2 u = a[j], v = w2[j];
            s += u.x * v.x + u.y * v.y;
        }
        colsum[tid] = s + 16.f * out_b[tid];
    }
    __syncthreads();

    if (tid < 16) {
        const float2* a = (const float2*)&eeg[tid][0];
        const float2* c = (const float2*)&colsum[0];
        float s = 0.f;
        for (int j = 0; j < 59; ++j) {
            float2 u = a[j], v = c[j];
            s += u.x * v.x + u.y * v.y;
        }
        Ssum[tid] = s;
    }
    __syncthreads();

    if (tid == 0) {
        int best = 0; float bv = Ssum[0];
        for (int i = 1; i < 16; ++i)
            if (Ssum[i] > bv) { bv = Ssum[i]; best = i; }    // first-max (jnp.argmax)
        sel = best;
    }
    __syncthreads();

    if (tid < OFC) {
        float s = 0.f;
        for (int t = 0; t < TDN; ++t) s += attn[sel][t] * vp[t][tid];
        avsel[tid] = s;
    }
    __syncthreads();

    if (tid < OFC) {
        const float2* a  = (const float2*)&avsel[0];
        const float2* w2 = (const float2*)&w[tid * OFC];
        float s = 0.f;
        #pragma unroll 4
        for (int j = 0; j < 59; ++j) {
            float2 u = a[j], v = w2[j];
            s += u.x * v.x + u.y * v.y;
        }
        ws[(b ? WS_ATT_B : WS_ATT_A) + tid] = s + out_b[tid];
    }
}

// ---------------------------------------------------------------------------
// Kernel 3: the four 16-dim cross MHAs + conv + relu + max. One block each.
// ---------------------------------------------------------------------------
__global__ __launch_bounds__(256) void branch_kernel(
    const float* __restrict__ x,
    const float* __restrict__ wsf,
    const float* __restrict__ cm_in_w, const float* __restrict__ cm_in_b,
    const float* __restrict__ cm_out_w, const float* __restrict__ cm_out_b,
    const float* __restrict__ projA_w, const float* __restrict__ projB_w,
    const float* __restrict__ conv_w, const float* __restrict__ conv_b,
    float* __restrict__ feats)
{
    const int br  = blockIdx.x;
    const int tid = threadIdx.x;

    __shared__ float arow[2][OFC];      // selected attA / attB rows
    __shared__ float pvec[2][16];       // projA_w, projB_w
    __shared__ float eeg_s[16][121];    // eeg, padded (odd stride)
    __shared__ float w_inT[16][48];     // transposed cm_in_w[br]: [r][q]
    __shared__ float b_in[48];
    __shared__ float tv[3][16];         // hoisted rank-1 projection per section
    __shared__ float w_out[16 * 16];
    __shared__ float b_out[16];
    __shared__ float qkv[3 * OFC * 16]; // qp|kp|vp; later aliased as softmax partials
    __shared__ float o2[OFC][17];       // attn output rows (padded)
    __shared__ float cw[COUT * 16 * KS];
    __shared__ float cb[COUT];
    __shared__ float y[COUT][112];

    // ---- stage parameters + inputs ----
    for (int e = tid; e < 2 * OFC; e += 256) {
        int wch = e / OFC, j = e % OFC;
        arow[wch][j] = wsf[(wch ? WS_ATT_B : WS_ATT_A) + j];
    }
    if (tid < 16) { pvec[0][tid] = projA_w[tid]; pvec[1][tid] = projB_w[tid]; }
    for (int e = tid; e < 16 * OFC; e += 256) {
        int r = e / OFC, c = e % OFC;
        eeg_s[r][c] = x[(1 + r) * WL + (WL - OFC) + c];
    }
    for (int e = tid; e < 768; e += 256) {
        int q = e / 16, r = e % 16;
        w_inT[r][q] = cm_in_w[br * 768 + e];
    }
    if (tid < 48) b_in[tid] = cm_in_b[br * 48 + tid];
    w_out[tid & 255] = cm_out_w[br * 256 + (tid & 255)];
    if (tid < 16) b_out[tid] = cm_out_b[br * 16 + tid];
    for (int e = tid; e < COUT * 16 * KS; e += 256) cw[e] = conv_w[br * COUT * 16 * KS + e];
    if (tid < COUT) cb[tid] = conv_b[br * COUT + tid];
    __syncthreads();

    // data/kv codes: 0=eeg, 1=wA, 2=wB
    int dcode, kcode;
    switch (br) {
        case 0:  dcode = 1; kcode = 0; break;
        case 1:  dcode = 0; kcode = 1; break;
        case 2:  dcode = 0; kcode = 2; break;
        default: dcode = 2; kcode = 0; break;
    }

    // hoist: tv[sec][o] = sum_r pvec[code-1][r] * w_inT[r][sec*16+o]  (rank-1 data)
    if (tid < 48) {
        int sec = tid / 16, o = tid % 16;
        int code = (sec == 0) ? dcode : kcode;
        float s = 0.f;
        if (code != 0) {
            #pragma unroll
            for (int r = 0; r < 16; ++r) s += pvec[code - 1][r] * w_inT[r][sec * 16 + o];
        }
        tv[sec][o] = s;
    }
    __syncthreads();

    float* qp = qkv;
    float* kp = qkv + OFC * 16;
    float* vp = qkv + 2 * OFC * 16;

    // ---- q/k/v projections: 3 x 118 x 16, dot-16 (all LDS) ----
    for (int e = tid; e < 3 * OFC * 16; e += 256) {
        int sec = e / (OFC * 16);
        int rem = e - sec * OFC * 16;
        int j = rem / 16, o = rem % 16;
        int code = (sec == 0) ? dcode : kcode;
        float s;
        if (code == 0) {
            s = 0.f;
            #pragma unroll
            for (int r = 0; r < 16; ++r) s += eeg_s[r][j] * w_inT[r][sec * 16 + o];
        } else {
            s = tv[sec][o] * arow[code - 1][j];
        }
        s += b_in[sec * 16 + o];
        if (sec == 0) s *= 0.25f;       // 1/sqrt(16)
        qkv[e] = s;
    }
    __syncthreads();

    // ---- flash attention over 118 kv positions, 2 groups of 59 ----
    const int g = tid >> 7;             // 0 or 1
    const int j = tid & 127;            // q row
    float q[16], acc[16];
    float m = -INFINITY, l = 0.f;
    #pragma unroll
    for (int r = 0; r < 16; ++r) acc[r] = 0.f;

    if (j < OFC) {
        #pragma unroll
        for (int r = 0; r < 16; ++r) q[r] = qp[j * 16 + r];
        const int t0 = g * 59, t1 = t0 + 59;
        for (int t = t0; t < t1; ++t) {
            const float* krow = kp + t * 16;
            float s = 0.f;
            #pragma unroll
            for (int r = 0; r < 16; ++r) s += q[r] * krow[r];
            float mn = fmaxf(m, s);
            float c  = __expf(m - mn);  // first iter: exp(-inf)=0
            float p  = __expf(s - mn);
            l = l * c + p;
            const float* vrow = vp + t * 16;
            #pragma unroll
            for (int r = 0; r < 16; ++r) acc[r] = acc[r] * c + p * vrow[r];
            m = mn;
        }
    }
    __syncthreads();                    // all reads of qp/kp/vp complete

    // partials aliased over the (now dead) qkv region
    float* part_m   = qkv;              // [2][128]
    float* part_l   = qkv + 256;        // [2][128]
    float* part_acc = qkv + 512;        // [2][118][16]
    if (j < OFC) {
        part_m[g * 128 + j] = m;
        part_l[g * 128 + j] = l;
        #pragma unroll
        for (int r = 0; r < 16; ++r) part_acc[(g * OFC + j) * 16 + r] = acc[r];
    }
    __syncthreads();

    // merge + out-projection -> o2[j][c]
    if (tid < OFC) {
        float m0 = part_m[tid], m1 = part_m[128 + tid];
        float mm = fmaxf(m0, m1);
        float c0 = __expf(m0 - mm), c1 = __expf(m1 - mm);
        float ll = part_l[tid] * c0 + part_l[128 + tid] * c1;
        float inv = 1.f / ll;
        float orow[16];
        #pragma unroll
        for (int r = 0; r < 16; ++r)
            orow[r] = (part_acc[tid * 16 + r] * c0 + part_acc[(OFC + tid) * 16 + r] * c1) * inv;
        for (int c = 0; c < 16; ++c) {
            float s = b_out[c];
            #pragma unroll
            for (int mI = 0; mI < 16; ++mI) s += orow[mI] * w_out[c * 16 + mI];
            o2[tid][c] = s;
        }
    }
    __syncthreads();

    // ---- conv (VALID, width 110) + relu ----
    for (int e = tid; e < COUT * 110; e += 256) {
        int c = e / 110, p = e % 110;
        float s = cb[c];
        for (int mI = 0; mI < 16; ++mI) {
            #pragma unroll
            for (int k = 0; k < KS; ++k)
                s += o2[p + k][mI] * cw[(c * 16 + mI) * KS + k];
        }
        y[c][p] = fmaxf(s, 0.f);
    }
    __syncthreads();

    // ---- max over positions ----
    if (tid < COUT) {
        float mx = y[tid][0];
        for (int p = 1; p < 110; ++p) mx = fmaxf(mx, y[tid][p]);
        feats[br * COUT + tid] = mx;
    }
}

// ---------------------------------------------------------------------------
// Kernel 4: 40 -> 40 -> 2 sigmoid head
// ---------------------------------------------------------------------------
__global__ __launch_bounds__(64) void head_kernel(
    const float* __restrict__ feats,
    const float* __restrict__ fc1_w, const float* __restrict__ fc1_b,
    const float* __restrict__ fc2_w, const float* __restrict__ fc2_b,
    float* __restrict__ out)
{
    __shared__ float flat[40];
    __shared__ float h[40];
    const int tid = threadIdx.x;
    if (tid < 40) flat[tid] = feats[tid];
    __syncthreads();
    if (tid < 40) {
        float s = fc1_b[tid];
        for (int k = 0; k < 40; ++k) s += flat[k] * fc1_w[tid * 40 + k];
        h[tid] = 1.f / (1.f + __expf(-s));
    }
    __syncthreads();
    if (tid < 2) {
        float s = fc2_b[tid];
        for (int k = 0; k < 40; ++k) s += h[k] * fc2_w[tid * 40 + k];
        out[tid] = 1.f / (1.f + __expf(-s));
    }
}

// ---------------------------------------------------------------------------
extern "C" void kernel_launch(void* const* d_in, const int* in_sizes, int n_in,
                              void* d_out, int out_size, void* d_ws, size_t ws_size,
                              hipStream_t stream) {
    const float* x        = (const float*)d_in[0];
    const float* tdA_in_w = (const float*)d_in[1];
    const float* tdA_in_b = (const float*)d_in[2];
    const float* tdA_out_w= (const float*)d_in[3];
    const float* tdA_out_b= (const float*)d_in[4];
    const float* tdB_in_w = (const float*)d_in[5];
    const float* tdB_in_b = (const float*)d_in[6];
    const float* tdB_out_w= (const float*)d_in[7];
    const float* tdB_out_b= (const float*)d_in[8];
    const float* cm_in_w  = (const float*)d_in[9];
    const float* cm_in_b  = (const float*)d_in[10];
    const float* cm_out_w = (const float*)d_in[11];
    const float* cm_out_b = (const float*)d_in[12];
    const float* projA_w  = (const float*)d_in[13];
    const float* projB_w  = (const float*)d_in[14];
    const float* conv_w   = (const float*)d_in[15];
    const float* conv_b   = (const float*)d_in[16];
    const float* fc1_w    = (const float*)d_in[17];
    const float* fc1_b    = (const float*)d_in[18];
    const float* fc2_w    = (const float*)d_in[19];
    const float* fc2_b    = (const float*)d_in[20];

    float* ws  = (float*)d_ws;
    float* out = (float*)d_out;

    td_proj_kernel<<<6, 512, 0, stream>>>(x,
        tdA_in_w, tdA_in_b, tdB_in_w, tdB_in_b, ws);

    td_attn_kernel<<<2, 512, 0, stream>>>(x,
        tdA_out_w, tdA_out_b, tdB_out_w, tdB_out_b, ws);

    branch_kernel<<<4, 256, 0, stream>>>(x, ws,
        cm_in_w, cm_in_b, cm_out_w, cm_out_b,
        projA_w, projB_w, conv_w, conv_b, ws + WS_FEATS);

    head_kernel<<<1, 64, 0, stream>>>(ws + WS_FEATS,
        fc1_w, fc1_b, fc2_w, fc2_b, out);
}